// Round 18
// baseline (298.798 us; speedup 1.0000x reference)
//
#include <hip/hip_runtime.h>

#define NN 100000
#define NE 1600000
#define FIN 256
#define FHID 128
#define FCLS 64

// multisplit params: 512 nodes per partition
#define SH1 9
#define P1 196
#define EPB_H 2048
#define NBH ((NE + EPB_H - 1) / EPB_H)   // 782 fine histogram rows
#define EPB_P 4096
#define NBP ((NE + EPB_P - 1) / EPB_P)   // 391 place blocks (2 fine rows each)
#define BROWS 4                          // fine rows per thread in colscan (782 <= 256*4)

typedef _Float16 f16;
typedef __attribute__((ext_vector_type(8))) _Float16 f16x8;
typedef __attribute__((ext_vector_type(2))) _Float16 f16x2;
typedef __attribute__((ext_vector_type(4))) float f32x4;
typedef __attribute__((ext_vector_type(2))) float f32x2;

// ---------------- pass A: per-block dual histogram (dst part + src part), NO global atomics ----
__global__ __launch_bounds__(256) void k_histA(const int* __restrict__ src, const int* __restrict__ dst,
                                               int* __restrict__ hist2d, int* __restrict__ shist2d) {
  __shared__ int lh[P1], lhS[P1];
  int t = threadIdx.x;
  for (int i = t; i < P1; i += 256) { lh[i] = 0; lhS[i] = 0; }
  __syncthreads();
  int base = blockIdx.x * EPB_H;
  int cnt = NE - base; if (cnt > EPB_H) cnt = EPB_H;
  for (int i = t; i < cnt; i += 256) {
    atomicAdd(&lh[dst[base + i] >> SH1], 1);
    atomicAdd(&lhS[src[base + i] >> SH1], 1);
  }
  __syncthreads();
  for (int i = t; i < P1; i += 256) {
    hist2d[blockIdx.x * P1 + i] = lh[i];
    shist2d[blockIdx.x * P1 + i] = lhS[i];
  }
}

// ---------------- pass B1: per-partition column scan (dst cols AND src cols) ----------------
__global__ __launch_bounds__(256) void k_colscan2(const int* __restrict__ hist2d, const int* __restrict__ shist2d,
                                                  int* __restrict__ colpre, int* __restrict__ colpreS,
                                                  int* __restrict__ totals, int* __restrict__ totalsS) {
  __shared__ int sm[256];
  int bp = blockIdx.x;
  bool isS = bp >= P1;
  int p = isS ? bp - P1 : bp;
  const int* h = isS ? shist2d : hist2d;
  int* cp = isS ? colpreS : colpre;
  int* tt = isS ? totalsS : totals;
  int t = threadIdx.x;
  int vals[BROWS];
  int lsum = 0;
  int b0 = t * BROWS;
#pragma unroll
  for (int i = 0; i < BROWS; ++i) {
    int b = b0 + i;
    int v = (b < NBH) ? h[b * P1 + p] : 0;
    vals[i] = v;
    lsum += v;
  }
  int x = lsum;
  sm[t] = x;
  __syncthreads();
  for (int off = 1; off < 256; off <<= 1) {
    int y = (t >= off) ? sm[t - off] : 0;
    __syncthreads();
    x += y;
    sm[t] = x;
    __syncthreads();
  }
  int run = x - lsum;
#pragma unroll
  for (int i = 0; i < BROWS; ++i) {
    int b = b0 + i;
    if (b < NBH) cp[b * P1 + p] = run;
    run += vals[i];
  }
  if (t == 255) tt[p] = x;
}

// ---------------- pass B2: partition-total exclusive scans (both) ----------------
__global__ __launch_bounds__(256) void k_pbase2(const int* __restrict__ totals, const int* __restrict__ totalsS,
                                                int* __restrict__ pbase, int* __restrict__ pbaseS,
                                                int* __restrict__ rp) {
  __shared__ int sm[256];
  int t = threadIdx.x;
  int v = (t < P1) ? totals[t] : 0;
  int x = v;
  sm[t] = x;
  __syncthreads();
  for (int off = 1; off < 256; off <<= 1) {
    int y = (t >= off) ? sm[t - off] : 0;
    __syncthreads();
    x += y;
    sm[t] = x;
    __syncthreads();
  }
  if (t < P1) pbase[t] = x - v;
  __syncthreads();
  int vS = (t < P1) ? totalsS[t] : 0;
  int xS = vS;
  sm[t] = xS;
  __syncthreads();
  for (int off = 1; off < 256; off <<= 1) {
    int y = (t >= off) ? sm[t - off] : 0;
    __syncthreads();
    xS += y;
    sm[t] = xS;
    __syncthreads();
  }
  if (t < P1) pbaseS[t] = xS - vS;
  if (t == 0) rp[NN] = NE;
}

// ---------------- pass C: dual LDS counting sort (dst pairs + src u16) ----------------
__global__ __launch_bounds__(256) void k_place(const int* __restrict__ src, const int* __restrict__ dst,
                                               const int* __restrict__ hist2d, const int* __restrict__ shist2d,
                                               const int* __restrict__ colpre, const int* __restrict__ colpreS,
                                               const int* __restrict__ pbase, const int* __restrict__ pbaseS,
                                               unsigned* __restrict__ staged, unsigned short* __restrict__ stagedS) {
  __shared__ unsigned buf[EPB_P];
  __shared__ unsigned bufS[EPB_P];
  __shared__ unsigned char prt[EPB_P];
  __shared__ int lofs[P1], lcur[P1], lbase[P1];
  __shared__ int lofsS[P1], lcurS[P1], lbaseS[P1];
  __shared__ int sm[256];
  int t = threadIdx.x;
  int b = blockIdx.x;
  int f0 = 2 * b, f1 = 2 * b + 1;
  int v = 0, vS = 0;
  if (t < P1) {
    v = hist2d[f0 * P1 + t];
    vS = shist2d[f0 * P1 + t];
    if (f1 < NBH) { v += hist2d[f1 * P1 + t]; vS += shist2d[f1 * P1 + t]; }
    lbase[t] = pbase[t] + colpre[f0 * P1 + t];
    lbaseS[t] = pbaseS[t] + colpreS[f0 * P1 + t];
    lcur[t] = 0;
    lcurS[t] = 0;
  }
  int x = v;
  sm[t] = x;
  __syncthreads();
  for (int off = 1; off < 256; off <<= 1) {
    int y = (t >= off) ? sm[t - off] : 0;
    __syncthreads();
    x += y;
    sm[t] = x;
    __syncthreads();
  }
  if (t < P1) lofs[t] = x - v;
  __syncthreads();
  int xS = vS;
  sm[t] = xS;
  __syncthreads();
  for (int off = 1; off < 256; off <<= 1) {
    int y = (t >= off) ? sm[t - off] : 0;
    __syncthreads();
    xS += y;
    sm[t] = xS;
    __syncthreads();
  }
  if (t < P1) lofsS[t] = xS - vS;
  __syncthreads();

  int base = b * EPB_P;
  int cnt = NE - base; if (cnt > EPB_P) cnt = EPB_P;
  for (int i = t; i < cnt; i += 256) {
    int s = src[base + i], d = dst[base + i];
    int p = d >> SH1;
    int pos = lofs[p] + atomicAdd(&lcur[p], 1);
    buf[pos] = ((unsigned)s << SH1) | (unsigned)(d & 511);
    prt[pos] = (unsigned char)p;
    int pS = s >> SH1;
    int posS = lofsS[pS] + atomicAdd(&lcurS[pS], 1);
    bufS[posS] = (unsigned)s;
  }
  __syncthreads();
  for (int i = t; i < cnt; i += 256) {
    int p = prt[i];
    staged[lbase[p] + (i - lofs[p])] = buf[i];
    unsigned sv = bufS[i];
    int pS = sv >> SH1;
    stagedS[lbaseS[pS] + (i - lofsS[pS])] = (unsigned short)(sv & 511);
  }
}

// ---------------- pass D: per-partition CSR build (+ inorm) ----------------
__global__ __launch_bounds__(512) void k_buildp(const unsigned* __restrict__ staged, const int* __restrict__ totals,
                                                const int* __restrict__ pbase, int* __restrict__ rp,
                                                float* __restrict__ inorm, int* __restrict__ csr) {
  __shared__ int lcnt[512], lofs[512], lcur[512];
  int p = blockIdx.x, t = threadIdx.x;
  int pb = pbase[p], cnt = totals[p];
  lcnt[t] = 0;
  __syncthreads();
  const unsigned* sp = staged + pb;
  for (int i = t; i < cnt; i += 512) atomicAdd(&lcnt[sp[i] & 511], 1);
  __syncthreads();
  int v = lcnt[t];
  int x = v;
  lofs[t] = x;
  __syncthreads();
  for (int off = 1; off < 512; off <<= 1) {
    int y = (t >= off) ? lofs[t - off] : 0;
    __syncthreads();
    x += y;
    lofs[t] = x;
    __syncthreads();
  }
  int excl = x - v;
  lofs[t] = excl;
  lcur[t] = 0;
  int node = (p << SH1) + t;
  if (node < NN) {
    rp[node] = pb + excl;
    int dg = v < 1 ? 1 : v;
    inorm[node] = rsqrtf((float)dg);
  }
  __syncthreads();
  for (int i = t; i < cnt; i += 512) {
    unsigned e = sp[i];
    int d = e & 511;
    int pos = pb + lofs[d] + atomicAdd(&lcur[d], 1);
    csr[pos] = (int)(e >> SH1);
  }
}

// ---------------- pass E: per-partition src count -> onorm ----------------
__global__ __launch_bounds__(512) void k_countS(const unsigned short* __restrict__ stagedS,
                                                const int* __restrict__ totalsS, const int* __restrict__ pbaseS,
                                                float* __restrict__ onorm) {
  __shared__ int lcnt[512];
  int p = blockIdx.x, t = threadIdx.x;
  int pb = pbaseS[p], cnt = totalsS[p];
  lcnt[t] = 0;
  __syncthreads();
  const unsigned short* sp = stagedS + pb;
  for (int i = t; i < cnt; i += 512) atomicAdd(&lcnt[sp[i]], 1);
  __syncthreads();
  int node = (p << SH1) + t;
  if (node < NN) {
    int od = lcnt[t];
    if (od < 1) od = 1;
    onorm[node] = rsqrtf((float)od);
  }
}

// ---------------- cast: x (f32 row-major) * onorm -> xh (f16 sliced-32), pure streaming ------
__global__ __launch_bounds__(256) void k_cast(const float* __restrict__ x, const float* __restrict__ onorm,
                                              f16* __restrict__ xh) {
  int g = blockIdx.x * 256 + threadIdx.x;
  if (g >= NN * 32) return;
  int node = g >> 5;
  int ko = (g & 31) * 8;
  int slice = ko >> 5;
  int j = ko & 31;
  float on = onorm[node];
  const float* xp = x + (size_t)node * FIN + ko;
  f32x4 v0 = *(const f32x4*)xp;
  f32x4 v1 = *(const f32x4*)(xp + 4);
  f16x8 o;
#pragma unroll
  for (int i = 0; i < 4; ++i) {
    o[i] = (f16)(v0[i] * on);
    o[4 + i] = (f16)(v1[i] * on);
  }
  *(f16x8*)(xh + ((size_t)slice * NN + node) * 32 + j) = o;
}

// ---------------- weight pack: fragment-major f16 for mfma 16x16x32 ----------------
template <int K, int NW>
__global__ __launch_bounds__(256) void k_packw(const float* __restrict__ W, f16* __restrict__ Wp) {
  int idx = blockIdx.x * 256 + threadIdx.x;
  if (idx >= K * NW) return;
  constexpr int nT = NW / 16;
  int i = idx & 7;
  int l = (idx >> 3) & 63;
  int rest = idx >> 9;
  int t = rest % nT;
  int s = rest / nT;
  int k = s * 32 + (l >> 4) * 8 + i;
  int n = t * 16 + (l & 15);
  Wp[idx] = (f16)W[k * NW + n];
}

// ---------------- GEMM: [M=NN x K] @ [K x NW] via mfma_f32_16x16x32_f16 ----------------
// Plain in-loop A loads (R14-proven codegen; no prefetch window — R15/R16 lesson:
// register prefetch costs VGPR/occupancy and loses more than it gains here).
// I/O feature-sliced in 32-wide slices: T[slice][NN][32] f16 (A loads = 1KB/wave coalesced).
// MODE 0: A = f32 x (row-major), rows scaled by onorm (fallback if ws too small).
// MODE 1: A = f16 sliced-32, plain store.                (layers 1,3)
// MODE 2: A = f16 sliced-32; epilogue relu(+bias)*onorm. (layer 2)
template <int K, int NW, int MODE>
__global__ __launch_bounds__(256) void k_gemm(const void* __restrict__ Asrc, const f16* __restrict__ Wp,
                                              const float* __restrict__ onorm, const float* __restrict__ bias,
                                              f16* __restrict__ Out) {
  constexpr int nS = K / 32, nT = NW / 16;
  int lane = threadIdx.x & 63;
  int w = threadIdx.x >> 6;
  int bm = blockIdx.x * 64 + w * 16;
  int arow = bm + (lane & 15);
  int koff = (lane >> 4) * 8;
  bool rowok = arow < NN;

  f32x4 acc[nT];
#pragma unroll
  for (int t = 0; t < nT; ++t) acc[t] = (f32x4){0.f, 0.f, 0.f, 0.f};

  float ascale = 0.0f;
  if (MODE == 0) ascale = rowok ? onorm[arow] : 0.0f;

  for (int s = 0; s < nS; ++s) {
    f16x8 a = {};
    if (rowok) {
      if (MODE == 0) {
        const float* ap = (const float*)Asrc + (size_t)arow * K + s * 32 + koff;
        f32x4 v0 = *(const f32x4*)ap;
        f32x4 v1 = *(const f32x4*)(ap + 4);
#pragma unroll
        for (int j = 0; j < 4; ++j) {
          a[j] = (f16)(v0[j] * ascale);
          a[4 + j] = (f16)(v1[j] * ascale);
        }
      } else {
        // sliced-32 A: k-subtile s IS slice s
        a = *(const f16x8*)((const f16*)Asrc + ((size_t)s * NN + arow) * 32 + koff);
      }
    }
    const f16* bp = Wp + ((size_t)(s * nT) * 64 + lane) * 8;
#pragma unroll
    for (int t = 0; t < nT; ++t) {
      f16x8 bfr = *(const f16x8*)(bp + t * 512);
      acc[t] = __builtin_amdgcn_mfma_f32_16x16x32_f16(a, bfr, acc[t], 0, 0, 0);
    }
  }

  int crow0 = bm + (lane >> 4) * 4;
  int ccol = lane & 15;
#pragma unroll
  for (int t = 0; t < nT; ++t) {
#pragma unroll
    for (int r = 0; r < 4; ++r) {
      int row = crow0 + r;
      if (row >= NN) continue;
      int col = t * 16 + ccol;
      float v = acc[t][r];
      if (MODE == 2) v = fmaxf(v + bias[col], 0.f) * onorm[row];
      Out[((size_t)(col >> 5) * NN + row) * 32 + (col & 31)] = (f16)v;
    }
  }
}

// ---------------- sliced aggregation: 64B rows, 4 lanes/node, LDS-staged indices ----------
#define LCSR_CAP 1408  // 64 nodes * mean 16 = 1024, sigma 32 -> +12 sigma
template <int NS, int MODE>
__global__ __launch_bounds__(256) void k_aggs(const f16* __restrict__ src_arr, const int* __restrict__ rp,
                                              const int* __restrict__ csr, const float* __restrict__ inorm,
                                              const float* __restrict__ onorm, const float* __restrict__ bias,
                                              void* __restrict__ outp) {
  constexpr int XPS = 8 / NS;              // XCDs per slice
  constexpr int BPS = (NN + 63) / 64;      // node-groups per slice = 1563
  __shared__ int lcsr[LCSR_CAP];
  int bid = blockIdx.x;
  int r = bid & 7;
  int slice = r / XPS;
  int w = (bid >> 3) * XPS + (r % XPS);
  if (w >= BPS) return;                    // uniform per block
  int t = threadIdx.x;
  int nbase = w * 64;
  int nlim = nbase + 64; if (nlim > NN) nlim = NN;
  int first = rp[nbase];
  int last = rp[nlim];
  int span = last - first;
  bool useLds = (span <= LCSR_CAP);
  if (useLds) {
    for (int i = t; i < span; i += 256) lcsr[i] = csr[first + i];
  }
  __syncthreads();
  int node = nbase + (t >> 2);
  if (node >= NN) return;
  int q = t & 3;                           // quarter of the 64B row
  int beg = rp[node], end = rp[node + 1];
  const char* sbp = (const char*)src_arr + ((size_t)slice * NN * 32 + q * 8) * 2;

  float acc[8];
#pragma unroll
  for (int j = 0; j < 8; ++j) acc[j] = 0.f;

  if (useLds) {
    int le = beg - first, lend = end - first;
    for (; le + 7 < lend; le += 8) {
      int x0 = lcsr[le], x1 = lcsr[le + 1], x2 = lcsr[le + 2], x3 = lcsr[le + 3];
      int x4 = lcsr[le + 4], x5 = lcsr[le + 5], x6 = lcsr[le + 6], x7 = lcsr[le + 7];
      f16x8 v0 = *(const f16x8*)(sbp + ((size_t)(unsigned)x0 << 6));
      f16x8 v1 = *(const f16x8*)(sbp + ((size_t)(unsigned)x1 << 6));
      f16x8 v2 = *(const f16x8*)(sbp + ((size_t)(unsigned)x2 << 6));
      f16x8 v3 = *(const f16x8*)(sbp + ((size_t)(unsigned)x3 << 6));
      f16x8 v4 = *(const f16x8*)(sbp + ((size_t)(unsigned)x4 << 6));
      f16x8 v5 = *(const f16x8*)(sbp + ((size_t)(unsigned)x5 << 6));
      f16x8 v6 = *(const f16x8*)(sbp + ((size_t)(unsigned)x6 << 6));
      f16x8 v7 = *(const f16x8*)(sbp + ((size_t)(unsigned)x7 << 6));
#pragma unroll
      for (int j = 0; j < 8; ++j) {
        float s01 = (float)v0[j] + (float)v1[j];
        float s23 = (float)v2[j] + (float)v3[j];
        float s45 = (float)v4[j] + (float)v5[j];
        float s67 = (float)v6[j] + (float)v7[j];
        acc[j] += (s01 + s23) + (s45 + s67);
      }
    }
    for (; le + 3 < lend; le += 4) {
      int x0 = lcsr[le], x1 = lcsr[le + 1], x2 = lcsr[le + 2], x3 = lcsr[le + 3];
      f16x8 v0 = *(const f16x8*)(sbp + ((size_t)(unsigned)x0 << 6));
      f16x8 v1 = *(const f16x8*)(sbp + ((size_t)(unsigned)x1 << 6));
      f16x8 v2 = *(const f16x8*)(sbp + ((size_t)(unsigned)x2 << 6));
      f16x8 v3 = *(const f16x8*)(sbp + ((size_t)(unsigned)x3 << 6));
#pragma unroll
      for (int j = 0; j < 8; ++j)
        acc[j] += ((float)v0[j] + (float)v1[j]) + ((float)v2[j] + (float)v3[j]);
    }
    for (; le < lend; ++le) {
      f16x8 v0 = *(const f16x8*)(sbp + ((size_t)(unsigned)lcsr[le] << 6));
#pragma unroll
      for (int j = 0; j < 8; ++j) acc[j] += (float)v0[j];
    }
  } else {
    for (int e = beg; e < end; ++e) {
      f16x8 v0 = *(const f16x8*)(sbp + ((size_t)(unsigned)csr[e] << 6));
#pragma unroll
      for (int j = 0; j < 8; ++j) acc[j] += (float)v0[j];
    }
  }

  float inn = inorm[node];
  int gfb = slice * 32 + q * 8;            // global feature col base
  if (MODE == 0) {
    float on = onorm[node];
    f16x8 o;
#pragma unroll
    for (int j = 0; j < 8; ++j) o[j] = (f16)(fmaxf(acc[j] * inn + bias[gfb + j], 0.f) * on);
    *(f16x8*)((f16*)outp + ((size_t)slice * NN + node) * 32 + q * 8) = o;
  } else if (MODE == 1) {
    f16x8 o;
#pragma unroll
    for (int j = 0; j < 8; ++j) o[j] = (f16)(acc[j] * inn);
    *(f16x8*)((f16*)outp + ((size_t)slice * NN + node) * 32 + q * 8) = o;
  } else {
    float* op = (float*)outp + (size_t)node * (NS * 32) + gfb;
    f32x4 o0, o1;
#pragma unroll
    for (int j = 0; j < 4; ++j) {
      o0[j] = acc[j] * inn + bias[gfb + j];
      o1[j] = acc[4 + j] * inn + bias[gfb + 4 + j];
    }
    *(f32x4*)op = o0;
    *(f32x4*)(op + 4) = o1;
  }
}

extern "C" void kernel_launch(void* const* d_in, const int* in_sizes, int n_in,
                              void* d_out, int out_size, void* d_ws, size_t ws_size,
                              hipStream_t stream) {
  const float* x = (const float*)d_in[0];
  const int* src = (const int*)d_in[1];
  const int* dst = (const int*)d_in[2];
  const float* W1 = (const float*)d_in[3];
  const float* b1 = (const float*)d_in[4];
  const float* W2 = (const float*)d_in[5];
  const float* b2 = (const float*)d_in[6];
  const float* W3 = (const float*)d_in[7];
  const float* b3 = (const float*)d_in[8];

  char* base = (char*)d_ws;
  size_t off = 0;
  auto take = [&](size_t bytes) -> void* {
    void* r = base + off;
    off += (bytes + 255) & ~(size_t)255;
    return r;
  };
  float* onorm = (float*)take((size_t)NN * 4);
  float* inorm = (float*)take((size_t)NN * 4);
  int* rp = (int*)take((size_t)(NN + 1) * 4);
  int* totals = (int*)take((size_t)P1 * 4);
  int* totalsS = (int*)take((size_t)P1 * 4);
  int* pbase = (int*)take((size_t)P1 * 4);
  int* pbaseS = (int*)take((size_t)P1 * 4);
  int* hist2d = (int*)take((size_t)NBH * P1 * 4);
  int* shist2d = (int*)take((size_t)NBH * P1 * 4);
  int* colpre = (int*)take((size_t)NBH * P1 * 4);
  int* colpreS = (int*)take((size_t)NBH * P1 * 4);
  unsigned* staged = (unsigned*)take((size_t)NE * 4);
  unsigned short* stagedS = (unsigned short*)take((size_t)NE * 2);
  int* csr = (int*)take((size_t)NE * 4);
  f16* W1p = (f16*)take((size_t)FIN * FHID * 2);
  f16* W2p = (f16*)take((size_t)FHID * FHID * 2);
  f16* W3p = (f16*)take((size_t)FHID * FCLS * 2);
  f16* B1 = (f16*)take((size_t)NN * FHID * 2);
  f16* B2 = (f16*)take((size_t)NN * FHID * 2);
  // xh (51.2 MB) only if workspace allows; else fall back to MODE-0 gemm on raw x
  size_t xh_bytes = (size_t)NN * FIN * 2;
  bool useCast = (off + xh_bytes + 256 <= ws_size);
  f16* xh = useCast ? (f16*)take(xh_bytes) : nullptr;

  k_histA<<<NBH, 256, 0, stream>>>(src, dst, hist2d, shist2d);
  k_colscan2<<<2 * P1, 256, 0, stream>>>(hist2d, shist2d, colpre, colpreS, totals, totalsS);
  k_pbase2<<<1, 256, 0, stream>>>(totals, totalsS, pbase, pbaseS, rp);
  k_place<<<NBP, 256, 0, stream>>>(src, dst, hist2d, shist2d, colpre, colpreS, pbase, pbaseS, staged, stagedS);
  k_buildp<<<P1, 512, 0, stream>>>(staged, totals, pbase, rp, inorm, csr);
  k_countS<<<P1, 512, 0, stream>>>(stagedS, totalsS, pbaseS, onorm);

  k_packw<FIN, FHID><<<(FIN * FHID + 255) / 256, 256, 0, stream>>>(W1, W1p);
  k_packw<FHID, FHID><<<(FHID * FHID + 255) / 256, 256, 0, stream>>>(W2, W2p);
  k_packw<FHID, FCLS><<<(FHID * FCLS + 255) / 256, 256, 0, stream>>>(W3, W3p);

  const int gemm_grid = (NN + 63) / 64;
  const int bps = (NN + 63) / 64;              // 1563
  const int agg4_grid = ((bps + 1) / 2) * 8;   // 6256 (NS=4, XPS=2)
  const int agg2_grid = ((bps + 3) / 4) * 8;   // 3128 (NS=2, XPS=4)

  // layer 1: t1 = (x*onorm) @ W1  -> sliced-32 B1 (4 slices)
  if (useCast) {
    k_cast<<<(NN * 32 + 255) / 256, 256, 0, stream>>>(x, onorm, xh);
    k_gemm<FIN, FHID, 1><<<gemm_grid, 256, 0, stream>>>(xh, W1p, nullptr, nullptr, B1);
  } else {
    k_gemm<FIN, FHID, 0><<<gemm_grid, 256, 0, stream>>>(x, W1p, onorm, nullptr, B1);
  }
  // g1 = relu(agg(t1)*inorm + b1) * onorm  -> sliced-32 B2
  k_aggs<4, 0><<<agg4_grid, 256, 0, stream>>>(B1, rp, csr, inorm, onorm, b1, B2);
  // agg2 = agg(g1)*inorm  -> sliced-32 B1
  k_aggs<4, 1><<<agg4_grid, 256, 0, stream>>>(B2, rp, csr, inorm, nullptr, nullptr, B1);
  // g2 = relu(agg2 @ W2 + b2) * onorm  -> sliced-32 B2
  k_gemm<FHID, FHID, 2><<<gemm_grid, 256, 0, stream>>>(B1, W2p, onorm, b2, B2);
  // t3 = g2 @ W3  -> sliced-32 B1 (2 slices used)
  k_gemm<FHID, FCLS, 1><<<gemm_grid, 256, 0, stream>>>(B2, W3p, nullptr, nullptr, B1);
  // out = agg(t3)*inorm + b3  -> dense f32 d_out
  k_aggs<2, 2><<<agg2_grid, 256, 0, stream>>>(B1, rp, csr, inorm, nullptr, b3, d_out);
}

// Round 19
// 294.345 us; speedup vs baseline: 1.0151x; 1.0151x over previous
//
#include <hip/hip_runtime.h>

#define NN 100000
#define NE 1600000
#define FIN 256
#define FHID 128
#define FCLS 64

// multisplit params: 512 nodes per partition
#define SH1 9
#define P1 196
#define EPB_H 2048
#define NBH ((NE + EPB_H - 1) / EPB_H)   // 782 fine histogram rows
#define EPB_P 4096
#define NBP ((NE + EPB_P - 1) / EPB_P)   // 391 place blocks (2 fine rows each)
#define BROWS 4                          // fine rows per thread in colscan (782 <= 256*4)

typedef _Float16 f16;
typedef __attribute__((ext_vector_type(8))) _Float16 f16x8;
typedef __attribute__((ext_vector_type(2))) _Float16 f16x2;
typedef __attribute__((ext_vector_type(4))) float f32x4;
typedef __attribute__((ext_vector_type(2))) float f32x2;

// ---------------- pass A: per-block dual histogram (dst part + src part), NO global atomics ----
__global__ __launch_bounds__(256) void k_histA(const int* __restrict__ src, const int* __restrict__ dst,
                                               int* __restrict__ hist2d, int* __restrict__ shist2d) {
  __shared__ int lh[P1], lhS[P1];
  int t = threadIdx.x;
  for (int i = t; i < P1; i += 256) { lh[i] = 0; lhS[i] = 0; }
  __syncthreads();
  int base = blockIdx.x * EPB_H;
  int cnt = NE - base; if (cnt > EPB_H) cnt = EPB_H;
  for (int i = t; i < cnt; i += 256) {
    atomicAdd(&lh[dst[base + i] >> SH1], 1);
    atomicAdd(&lhS[src[base + i] >> SH1], 1);
  }
  __syncthreads();
  for (int i = t; i < P1; i += 256) {
    hist2d[blockIdx.x * P1 + i] = lh[i];
    shist2d[blockIdx.x * P1 + i] = lhS[i];
  }
}

// ---------------- pass B1: per-partition column scan (dst cols AND src cols) ----------------
__global__ __launch_bounds__(256) void k_colscan2(const int* __restrict__ hist2d, const int* __restrict__ shist2d,
                                                  int* __restrict__ colpre, int* __restrict__ colpreS,
                                                  int* __restrict__ totals, int* __restrict__ totalsS) {
  __shared__ int sm[256];
  int bp = blockIdx.x;
  bool isS = bp >= P1;
  int p = isS ? bp - P1 : bp;
  const int* h = isS ? shist2d : hist2d;
  int* cp = isS ? colpreS : colpre;
  int* tt = isS ? totalsS : totals;
  int t = threadIdx.x;
  int vals[BROWS];
  int lsum = 0;
  int b0 = t * BROWS;
#pragma unroll
  for (int i = 0; i < BROWS; ++i) {
    int b = b0 + i;
    int v = (b < NBH) ? h[b * P1 + p] : 0;
    vals[i] = v;
    lsum += v;
  }
  int x = lsum;
  sm[t] = x;
  __syncthreads();
  for (int off = 1; off < 256; off <<= 1) {
    int y = (t >= off) ? sm[t - off] : 0;
    __syncthreads();
    x += y;
    sm[t] = x;
    __syncthreads();
  }
  int run = x - lsum;
#pragma unroll
  for (int i = 0; i < BROWS; ++i) {
    int b = b0 + i;
    if (b < NBH) cp[b * P1 + p] = run;
    run += vals[i];
  }
  if (t == 255) tt[p] = x;
}

// ---------------- pass B2: partition-total exclusive scans (both) ----------------
__global__ __launch_bounds__(256) void k_pbase2(const int* __restrict__ totals, const int* __restrict__ totalsS,
                                                int* __restrict__ pbase, int* __restrict__ pbaseS,
                                                int* __restrict__ rp) {
  __shared__ int sm[256];
  int t = threadIdx.x;
  int v = (t < P1) ? totals[t] : 0;
  int x = v;
  sm[t] = x;
  __syncthreads();
  for (int off = 1; off < 256; off <<= 1) {
    int y = (t >= off) ? sm[t - off] : 0;
    __syncthreads();
    x += y;
    sm[t] = x;
    __syncthreads();
  }
  if (t < P1) pbase[t] = x - v;
  __syncthreads();
  int vS = (t < P1) ? totalsS[t] : 0;
  int xS = vS;
  sm[t] = xS;
  __syncthreads();
  for (int off = 1; off < 256; off <<= 1) {
    int y = (t >= off) ? sm[t - off] : 0;
    __syncthreads();
    xS += y;
    sm[t] = xS;
    __syncthreads();
  }
  if (t < P1) pbaseS[t] = xS - vS;
  if (t == 0) rp[NN] = NE;
}

// ---------------- pass C: dual LDS counting sort (dst pairs + src u16) ----------------
__global__ __launch_bounds__(256) void k_place(const int* __restrict__ src, const int* __restrict__ dst,
                                               const int* __restrict__ hist2d, const int* __restrict__ shist2d,
                                               const int* __restrict__ colpre, const int* __restrict__ colpreS,
                                               const int* __restrict__ pbase, const int* __restrict__ pbaseS,
                                               unsigned* __restrict__ staged, unsigned short* __restrict__ stagedS) {
  __shared__ unsigned buf[EPB_P];
  __shared__ unsigned bufS[EPB_P];
  __shared__ unsigned char prt[EPB_P];
  __shared__ int lofs[P1], lcur[P1], lbase[P1];
  __shared__ int lofsS[P1], lcurS[P1], lbaseS[P1];
  __shared__ int sm[256];
  int t = threadIdx.x;
  int b = blockIdx.x;
  int f0 = 2 * b, f1 = 2 * b + 1;
  int v = 0, vS = 0;
  if (t < P1) {
    v = hist2d[f0 * P1 + t];
    vS = shist2d[f0 * P1 + t];
    if (f1 < NBH) { v += hist2d[f1 * P1 + t]; vS += shist2d[f1 * P1 + t]; }
    lbase[t] = pbase[t] + colpre[f0 * P1 + t];
    lbaseS[t] = pbaseS[t] + colpreS[f0 * P1 + t];
    lcur[t] = 0;
    lcurS[t] = 0;
  }
  int x = v;
  sm[t] = x;
  __syncthreads();
  for (int off = 1; off < 256; off <<= 1) {
    int y = (t >= off) ? sm[t - off] : 0;
    __syncthreads();
    x += y;
    sm[t] = x;
    __syncthreads();
  }
  if (t < P1) lofs[t] = x - v;
  __syncthreads();
  int xS = vS;
  sm[t] = xS;
  __syncthreads();
  for (int off = 1; off < 256; off <<= 1) {
    int y = (t >= off) ? sm[t - off] : 0;
    __syncthreads();
    xS += y;
    sm[t] = xS;
    __syncthreads();
  }
  if (t < P1) lofsS[t] = xS - vS;
  __syncthreads();

  int base = b * EPB_P;
  int cnt = NE - base; if (cnt > EPB_P) cnt = EPB_P;
  for (int i = t; i < cnt; i += 256) {
    int s = src[base + i], d = dst[base + i];
    int p = d >> SH1;
    int pos = lofs[p] + atomicAdd(&lcur[p], 1);
    buf[pos] = ((unsigned)s << SH1) | (unsigned)(d & 511);
    prt[pos] = (unsigned char)p;
    int pS = s >> SH1;
    int posS = lofsS[pS] + atomicAdd(&lcurS[pS], 1);
    bufS[posS] = (unsigned)s;
  }
  __syncthreads();
  for (int i = t; i < cnt; i += 256) {
    int p = prt[i];
    staged[lbase[p] + (i - lofs[p])] = buf[i];
    unsigned sv = bufS[i];
    int pS = sv >> SH1;
    stagedS[lbaseS[pS] + (i - lofsS[pS])] = (unsigned short)(sv & 511);
  }
}

// ---------------- pass D: per-partition CSR build (+ inorm) ----------------
__global__ __launch_bounds__(512) void k_buildp(const unsigned* __restrict__ staged, const int* __restrict__ totals,
                                                const int* __restrict__ pbase, int* __restrict__ rp,
                                                float* __restrict__ inorm, int* __restrict__ csr) {
  __shared__ int lcnt[512], lofs[512], lcur[512];
  int p = blockIdx.x, t = threadIdx.x;
  int pb = pbase[p], cnt = totals[p];
  lcnt[t] = 0;
  __syncthreads();
  const unsigned* sp = staged + pb;
  for (int i = t; i < cnt; i += 512) atomicAdd(&lcnt[sp[i] & 511], 1);
  __syncthreads();
  int v = lcnt[t];
  int x = v;
  lofs[t] = x;
  __syncthreads();
  for (int off = 1; off < 512; off <<= 1) {
    int y = (t >= off) ? lofs[t - off] : 0;
    __syncthreads();
    x += y;
    lofs[t] = x;
    __syncthreads();
  }
  int excl = x - v;
  lofs[t] = excl;
  lcur[t] = 0;
  int node = (p << SH1) + t;
  if (node < NN) {
    rp[node] = pb + excl;
    int dg = v < 1 ? 1 : v;
    inorm[node] = rsqrtf((float)dg);
  }
  __syncthreads();
  for (int i = t; i < cnt; i += 512) {
    unsigned e = sp[i];
    int d = e & 511;
    int pos = pb + lofs[d] + atomicAdd(&lcur[d], 1);
    csr[pos] = (int)(e >> SH1);
  }
}

// ---------------- pass E: per-partition src count -> onorm ----------------
__global__ __launch_bounds__(512) void k_countS(const unsigned short* __restrict__ stagedS,
                                                const int* __restrict__ totalsS, const int* __restrict__ pbaseS,
                                                float* __restrict__ onorm) {
  __shared__ int lcnt[512];
  int p = blockIdx.x, t = threadIdx.x;
  int pb = pbaseS[p], cnt = totalsS[p];
  lcnt[t] = 0;
  __syncthreads();
  const unsigned short* sp = stagedS + pb;
  for (int i = t; i < cnt; i += 512) atomicAdd(&lcnt[sp[i]], 1);
  __syncthreads();
  int node = (p << SH1) + t;
  if (node < NN) {
    int od = lcnt[t];
    if (od < 1) od = 1;
    onorm[node] = rsqrtf((float)od);
  }
}

// ---------------- weight pack: fragment-major f16 for mfma 16x16x32 ----------------
template <int K, int NW>
__global__ __launch_bounds__(256) void k_packw(const float* __restrict__ W, f16* __restrict__ Wp) {
  int idx = blockIdx.x * 256 + threadIdx.x;
  if (idx >= K * NW) return;
  constexpr int nT = NW / 16;
  int i = idx & 7;
  int l = (idx >> 3) & 63;
  int rest = idx >> 9;
  int t = rest % nT;
  int s = rest / nT;
  int k = s * 32 + (l >> 4) * 8 + i;
  int n = t * 16 + (l & 15);
  Wp[idx] = (f16)W[k * NW + n];
}

// ---------------- GEMM: [M=NN x K] @ [K x NW] via mfma_f32_16x16x32_f16 ----------------
// MODE 0 (layer 1): x f32 row-major staged through LDS — the 64x256 f32 block tile is
//   loaded as a dense 64KB sequential region (coalesced), scaled by onorm, stored f16
//   to a padded LDS tile; MFMA reads A fragments via ds_read_b128. Fixes the 1024B-stride
//   A-scatter that made MODE 0 latency-bound (R14: 64us @ VALUBusy 7%).
// MODE 1: A = f16 sliced-32, plain store.                (layer 3)
// MODE 2: A = f16 sliced-32; epilogue relu(+bias)*onorm. (layer 2)
#define XPITCH 264   // 256 + 8 f16 pad
template <int K, int NW, int MODE>
__global__ __launch_bounds__(256) void k_gemm(const void* __restrict__ Asrc, const f16* __restrict__ Wp,
                                              const float* __restrict__ onorm, const float* __restrict__ bias,
                                              f16* __restrict__ Out) {
  constexpr int nS = K / 32, nT = NW / 16;
  int lane = threadIdx.x & 63;
  int w = threadIdx.x >> 6;
  int bm = blockIdx.x * 64 + w * 16;
  int arow = bm + (lane & 15);
  int koff = (lane >> 4) * 8;
  bool rowok = arow < NN;

  __shared__ f16 axs[MODE == 0 ? 64 * XPITCH : 1];

  if (MODE == 0) {
    // stage 64x256 f32 tile -> scaled f16 LDS tile
    int t = threadIdx.x;
    int lrow = t >> 2;               // 0..63
    int cq = (t & 3) * 64;           // col base, 4 threads per row
    int grow = blockIdx.x * 64 + lrow;
    bool gok = grow < NN;
    float on = gok ? onorm[grow] : 0.0f;
    const float* xp = (const float*)Asrc + (size_t)grow * K + cq;
    f16* lp = axs + lrow * XPITCH + cq;
#pragma unroll
    for (int c = 0; c < 64; c += 8) {
      f32x4 v0 = {}, v1 = {};
      if (gok) {
        v0 = *(const f32x4*)(xp + c);
        v1 = *(const f32x4*)(xp + c + 4);
      }
      f16x8 o;
#pragma unroll
      for (int j = 0; j < 4; ++j) {
        o[j] = (f16)(v0[j] * on);
        o[4 + j] = (f16)(v1[j] * on);
      }
      *(f16x8*)(lp + c) = o;
    }
    __syncthreads();
  }

  f32x4 acc[nT];
#pragma unroll
  for (int t = 0; t < nT; ++t) acc[t] = (f32x4){0.f, 0.f, 0.f, 0.f};

  for (int s = 0; s < nS; ++s) {
    f16x8 a = {};
    if (MODE == 0) {
      a = *(const f16x8*)(axs + (w * 16 + (lane & 15)) * XPITCH + s * 32 + koff);
    } else if (rowok) {
      // sliced-32 A: k-subtile s IS slice s
      a = *(const f16x8*)((const f16*)Asrc + ((size_t)s * NN + arow) * 32 + koff);
    }
    const f16* bp = Wp + ((size_t)(s * nT) * 64 + lane) * 8;
#pragma unroll
    for (int t = 0; t < nT; ++t) {
      f16x8 bfr = *(const f16x8*)(bp + t * 512);
      acc[t] = __builtin_amdgcn_mfma_f32_16x16x32_f16(a, bfr, acc[t], 0, 0, 0);
    }
  }

  int crow0 = bm + (lane >> 4) * 4;
  int ccol = lane & 15;
#pragma unroll
  for (int t = 0; t < nT; ++t) {
#pragma unroll
    for (int r = 0; r < 4; ++r) {
      int row = crow0 + r;
      if (row >= NN) continue;
      int col = t * 16 + ccol;
      float v = acc[t][r];
      if (MODE == 2) v = fmaxf(v + bias[col], 0.f) * onorm[row];
      Out[((size_t)(col >> 5) * NN + row) * 32 + (col & 31)] = (f16)v;
    }
  }
}

// ---------------- sliced aggregation: 64B rows, 4 lanes/node, LDS-staged indices ----------
#define LCSR_CAP 1408  // 64 nodes * mean 16 = 1024, sigma 32 -> +12 sigma
template <int NS, int MODE>
__global__ __launch_bounds__(256) void k_aggs(const f16* __restrict__ src_arr, const int* __restrict__ rp,
                                              const int* __restrict__ csr, const float* __restrict__ inorm,
                                              const float* __restrict__ onorm, const float* __restrict__ bias,
                                              void* __restrict__ outp) {
  constexpr int XPS = 8 / NS;              // XCDs per slice
  constexpr int BPS = (NN + 63) / 64;      // node-groups per slice = 1563
  __shared__ int lcsr[LCSR_CAP];
  int bid = blockIdx.x;
  int r = bid & 7;
  int slice = r / XPS;
  int w = (bid >> 3) * XPS + (r % XPS);
  if (w >= BPS) return;                    // uniform per block
  int t = threadIdx.x;
  int nbase = w * 64;
  int nlim = nbase + 64; if (nlim > NN) nlim = NN;
  int first = rp[nbase];
  int last = rp[nlim];
  int span = last - first;
  bool useLds = (span <= LCSR_CAP);
  if (useLds) {
    for (int i = t; i < span; i += 256) lcsr[i] = csr[first + i];
  }
  __syncthreads();
  int node = nbase + (t >> 2);
  if (node >= NN) return;
  int q = t & 3;                           // quarter of the 64B row
  int beg = rp[node], end = rp[node + 1];
  const char* sbp = (const char*)src_arr + ((size_t)slice * NN * 32 + q * 8) * 2;

  float acc[8];
#pragma unroll
  for (int j = 0; j < 8; ++j) acc[j] = 0.f;

  if (useLds) {
    int le = beg - first, lend = end - first;
    for (; le + 7 < lend; le += 8) {
      int x0 = lcsr[le], x1 = lcsr[le + 1], x2 = lcsr[le + 2], x3 = lcsr[le + 3];
      int x4 = lcsr[le + 4], x5 = lcsr[le + 5], x6 = lcsr[le + 6], x7 = lcsr[le + 7];
      f16x8 v0 = *(const f16x8*)(sbp + ((size_t)(unsigned)x0 << 6));
      f16x8 v1 = *(const f16x8*)(sbp + ((size_t)(unsigned)x1 << 6));
      f16x8 v2 = *(const f16x8*)(sbp + ((size_t)(unsigned)x2 << 6));
      f16x8 v3 = *(const f16x8*)(sbp + ((size_t)(unsigned)x3 << 6));
      f16x8 v4 = *(const f16x8*)(sbp + ((size_t)(unsigned)x4 << 6));
      f16x8 v5 = *(const f16x8*)(sbp + ((size_t)(unsigned)x5 << 6));
      f16x8 v6 = *(const f16x8*)(sbp + ((size_t)(unsigned)x6 << 6));
      f16x8 v7 = *(const f16x8*)(sbp + ((size_t)(unsigned)x7 << 6));
#pragma unroll
      for (int j = 0; j < 8; ++j) {
        float s01 = (float)v0[j] + (float)v1[j];
        float s23 = (float)v2[j] + (float)v3[j];
        float s45 = (float)v4[j] + (float)v5[j];
        float s67 = (float)v6[j] + (float)v7[j];
        acc[j] += (s01 + s23) + (s45 + s67);
      }
    }
    for (; le + 3 < lend; le += 4) {
      int x0 = lcsr[le], x1 = lcsr[le + 1], x2 = lcsr[le + 2], x3 = lcsr[le + 3];
      f16x8 v0 = *(const f16x8*)(sbp + ((size_t)(unsigned)x0 << 6));
      f16x8 v1 = *(const f16x8*)(sbp + ((size_t)(unsigned)x1 << 6));
      f16x8 v2 = *(const f16x8*)(sbp + ((size_t)(unsigned)x2 << 6));
      f16x8 v3 = *(const f16x8*)(sbp + ((size_t)(unsigned)x3 << 6));
#pragma unroll
      for (int j = 0; j < 8; ++j)
        acc[j] += ((float)v0[j] + (float)v1[j]) + ((float)v2[j] + (float)v3[j]);
    }
    for (; le < lend; ++le) {
      f16x8 v0 = *(const f16x8*)(sbp + ((size_t)(unsigned)lcsr[le] << 6));
#pragma unroll
      for (int j = 0; j < 8; ++j) acc[j] += (float)v0[j];
    }
  } else {
    for (int e = beg; e < end; ++e) {
      f16x8 v0 = *(const f16x8*)(sbp + ((size_t)(unsigned)csr[e] << 6));
#pragma unroll
      for (int j = 0; j < 8; ++j) acc[j] += (float)v0[j];
    }
  }

  float inn = inorm[node];
  int gfb = slice * 32 + q * 8;            // global feature col base
  if (MODE == 0) {
    float on = onorm[node];
    f16x8 o;
#pragma unroll
    for (int j = 0; j < 8; ++j) o[j] = (f16)(fmaxf(acc[j] * inn + bias[gfb + j], 0.f) * on);
    *(f16x8*)((f16*)outp + ((size_t)slice * NN + node) * 32 + q * 8) = o;
  } else if (MODE == 1) {
    f16x8 o;
#pragma unroll
    for (int j = 0; j < 8; ++j) o[j] = (f16)(acc[j] * inn);
    *(f16x8*)((f16*)outp + ((size_t)slice * NN + node) * 32 + q * 8) = o;
  } else {
    float* op = (float*)outp + (size_t)node * (NS * 32) + gfb;
    f32x4 o0, o1;
#pragma unroll
    for (int j = 0; j < 4; ++j) {
      o0[j] = acc[j] * inn + bias[gfb + j];
      o1[j] = acc[4 + j] * inn + bias[gfb + 4 + j];
    }
    *(f32x4*)op = o0;
    *(f32x4*)(op + 4) = o1;
  }
}

extern "C" void kernel_launch(void* const* d_in, const int* in_sizes, int n_in,
                              void* d_out, int out_size, void* d_ws, size_t ws_size,
                              hipStream_t stream) {
  const float* x = (const float*)d_in[0];
  const int* src = (const int*)d_in[1];
  const int* dst = (const int*)d_in[2];
  const float* W1 = (const float*)d_in[3];
  const float* b1 = (const float*)d_in[4];
  const float* W2 = (const float*)d_in[5];
  const float* b2 = (const float*)d_in[6];
  const float* W3 = (const float*)d_in[7];
  const float* b3 = (const float*)d_in[8];

  char* base = (char*)d_ws;
  size_t off = 0;
  auto take = [&](size_t bytes) -> void* {
    void* r = base + off;
    off += (bytes + 255) & ~(size_t)255;
    return r;
  };
  float* onorm = (float*)take((size_t)NN * 4);
  float* inorm = (float*)take((size_t)NN * 4);
  int* rp = (int*)take((size_t)(NN + 1) * 4);
  int* totals = (int*)take((size_t)P1 * 4);
  int* totalsS = (int*)take((size_t)P1 * 4);
  int* pbase = (int*)take((size_t)P1 * 4);
  int* pbaseS = (int*)take((size_t)P1 * 4);
  int* hist2d = (int*)take((size_t)NBH * P1 * 4);
  int* shist2d = (int*)take((size_t)NBH * P1 * 4);
  int* colpre = (int*)take((size_t)NBH * P1 * 4);
  int* colpreS = (int*)take((size_t)NBH * P1 * 4);
  unsigned* staged = (unsigned*)take((size_t)NE * 4);
  unsigned short* stagedS = (unsigned short*)take((size_t)NE * 2);
  int* csr = (int*)take((size_t)NE * 4);
  f16* W1p = (f16*)take((size_t)FIN * FHID * 2);
  f16* W2p = (f16*)take((size_t)FHID * FHID * 2);
  f16* W3p = (f16*)take((size_t)FHID * FCLS * 2);
  f16* B1 = (f16*)take((size_t)NN * FHID * 2);
  f16* B2 = (f16*)take((size_t)NN * FHID * 2);

  k_histA<<<NBH, 256, 0, stream>>>(src, dst, hist2d, shist2d);
  k_colscan2<<<2 * P1, 256, 0, stream>>>(hist2d, shist2d, colpre, colpreS, totals, totalsS);
  k_pbase2<<<1, 256, 0, stream>>>(totals, totalsS, pbase, pbaseS, rp);
  k_place<<<NBP, 256, 0, stream>>>(src, dst, hist2d, shist2d, colpre, colpreS, pbase, pbaseS, staged, stagedS);
  k_buildp<<<P1, 512, 0, stream>>>(staged, totals, pbase, rp, inorm, csr);
  k_countS<<<P1, 512, 0, stream>>>(stagedS, totalsS, pbaseS, onorm);

  k_packw<FIN, FHID><<<(FIN * FHID + 255) / 256, 256, 0, stream>>>(W1, W1p);
  k_packw<FHID, FHID><<<(FHID * FHID + 255) / 256, 256, 0, stream>>>(W2, W2p);
  k_packw<FHID, FCLS><<<(FHID * FCLS + 255) / 256, 256, 0, stream>>>(W3, W3p);

  const int gemm_grid = (NN + 63) / 64;
  const int bps = (NN + 63) / 64;              // 1563
  const int agg4_grid = ((bps + 1) / 2) * 8;   // 6256 (NS=4, XPS=2)
  const int agg2_grid = ((bps + 3) / 4) * 8;   // 3128 (NS=2, XPS=4)

  // layer 1: t1 = (x*onorm) @ W1  -> sliced-32 B1 (4 slices), LDS-staged A
  k_gemm<FIN, FHID, 0><<<gemm_grid, 256, 0, stream>>>(x, W1p, onorm, nullptr, B1);
  // g1 = relu(agg(t1)*inorm + b1) * onorm  -> sliced-32 B2
  k_aggs<4, 0><<<agg4_grid, 256, 0, stream>>>(B1, rp, csr, inorm, onorm, b1, B2);
  // agg2 = agg(g1)*inorm  -> sliced-32 B1
  k_aggs<4, 1><<<agg4_grid, 256, 0, stream>>>(B2, rp, csr, inorm, nullptr, nullptr, B1);
  // g2 = relu(agg2 @ W2 + b2) * onorm  -> sliced-32 B2
  k_gemm<FHID, FHID, 2><<<gemm_grid, 256, 0, stream>>>(B1, W2p, onorm, b2, B2);
  // t3 = g2 @ W3  -> sliced-32 B1 (2 slices used)
  k_gemm<FHID, FCLS, 1><<<gemm_grid, 256, 0, stream>>>(B2, W3p, nullptr, nullptr, B1);
  // out = agg(t3)*inorm + b3  -> dense f32 d_out
  k_aggs<2, 2><<<agg2_grid, 256, 0, stream>>>(B1, rp, csr, inorm, nullptr, b3, d_out);
}

// Round 20
// 284.615 us; speedup vs baseline: 1.0498x; 1.0342x over previous
//
#include <hip/hip_runtime.h>

#define NN 100000
#define NE 1600000
#define FIN 256
#define FHID 128
#define FCLS 64

// multisplit params: 512 nodes per partition
#define SH1 9
#define P1 196
#define EPB_H 2048
#define NBH ((NE + EPB_H - 1) / EPB_H)   // 782 fine histogram rows
#define EPB_P 4096
#define NBP ((NE + EPB_P - 1) / EPB_P)   // 391 place blocks (2 fine rows each)
#define BROWS 4                          // fine rows per thread in colscan (782 <= 256*4)

typedef _Float16 f16;
typedef __attribute__((ext_vector_type(8))) _Float16 f16x8;
typedef __attribute__((ext_vector_type(2))) _Float16 f16x2;
typedef __attribute__((ext_vector_type(4))) float f32x4;
typedef __attribute__((ext_vector_type(2))) float f32x2;

// ---------------- pass A: per-block dual histogram (dst part + src part), NO global atomics ----
__global__ __launch_bounds__(256) void k_histA(const int* __restrict__ src, const int* __restrict__ dst,
                                               int* __restrict__ hist2d, int* __restrict__ shist2d) {
  __shared__ int lh[P1], lhS[P1];
  int t = threadIdx.x;
  for (int i = t; i < P1; i += 256) { lh[i] = 0; lhS[i] = 0; }
  __syncthreads();
  int base = blockIdx.x * EPB_H;
  int cnt = NE - base; if (cnt > EPB_H) cnt = EPB_H;
  for (int i = t; i < cnt; i += 256) {
    atomicAdd(&lh[dst[base + i] >> SH1], 1);
    atomicAdd(&lhS[src[base + i] >> SH1], 1);
  }
  __syncthreads();
  for (int i = t; i < P1; i += 256) {
    hist2d[blockIdx.x * P1 + i] = lh[i];
    shist2d[blockIdx.x * P1 + i] = lhS[i];
  }
}

// ---------------- pass B1: per-partition column scan (dst cols AND src cols) ----------------
__global__ __launch_bounds__(256) void k_colscan2(const int* __restrict__ hist2d, const int* __restrict__ shist2d,
                                                  int* __restrict__ colpre, int* __restrict__ colpreS,
                                                  int* __restrict__ totals, int* __restrict__ totalsS) {
  __shared__ int sm[256];
  int bp = blockIdx.x;
  bool isS = bp >= P1;
  int p = isS ? bp - P1 : bp;
  const int* h = isS ? shist2d : hist2d;
  int* cp = isS ? colpreS : colpre;
  int* tt = isS ? totalsS : totals;
  int t = threadIdx.x;
  int vals[BROWS];
  int lsum = 0;
  int b0 = t * BROWS;
#pragma unroll
  for (int i = 0; i < BROWS; ++i) {
    int b = b0 + i;
    int v = (b < NBH) ? h[b * P1 + p] : 0;
    vals[i] = v;
    lsum += v;
  }
  int x = lsum;
  sm[t] = x;
  __syncthreads();
  for (int off = 1; off < 256; off <<= 1) {
    int y = (t >= off) ? sm[t - off] : 0;
    __syncthreads();
    x += y;
    sm[t] = x;
    __syncthreads();
  }
  int run = x - lsum;
#pragma unroll
  for (int i = 0; i < BROWS; ++i) {
    int b = b0 + i;
    if (b < NBH) cp[b * P1 + p] = run;
    run += vals[i];
  }
  if (t == 255) tt[p] = x;
}

// ---------------- pass B2: partition-total exclusive scans (both) ----------------
__global__ __launch_bounds__(256) void k_pbase2(const int* __restrict__ totals, const int* __restrict__ totalsS,
                                                int* __restrict__ pbase, int* __restrict__ pbaseS,
                                                int* __restrict__ rp) {
  __shared__ int sm[256];
  int t = threadIdx.x;
  int v = (t < P1) ? totals[t] : 0;
  int x = v;
  sm[t] = x;
  __syncthreads();
  for (int off = 1; off < 256; off <<= 1) {
    int y = (t >= off) ? sm[t - off] : 0;
    __syncthreads();
    x += y;
    sm[t] = x;
    __syncthreads();
  }
  if (t < P1) pbase[t] = x - v;
  __syncthreads();
  int vS = (t < P1) ? totalsS[t] : 0;
  int xS = vS;
  sm[t] = xS;
  __syncthreads();
  for (int off = 1; off < 256; off <<= 1) {
    int y = (t >= off) ? sm[t - off] : 0;
    __syncthreads();
    xS += y;
    sm[t] = xS;
    __syncthreads();
  }
  if (t < P1) pbaseS[t] = xS - vS;
  if (t == 0) rp[NN] = NE;
}

// ---------------- pass C: dual LDS counting sort (dst pairs + src u16) ----------------
__global__ __launch_bounds__(256) void k_place(const int* __restrict__ src, const int* __restrict__ dst,
                                               const int* __restrict__ hist2d, const int* __restrict__ shist2d,
                                               const int* __restrict__ colpre, const int* __restrict__ colpreS,
                                               const int* __restrict__ pbase, const int* __restrict__ pbaseS,
                                               unsigned* __restrict__ staged, unsigned short* __restrict__ stagedS) {
  __shared__ unsigned buf[EPB_P];
  __shared__ unsigned bufS[EPB_P];
  __shared__ unsigned char prt[EPB_P];
  __shared__ int lofs[P1], lcur[P1], lbase[P1];
  __shared__ int lofsS[P1], lcurS[P1], lbaseS[P1];
  __shared__ int sm[256];
  int t = threadIdx.x;
  int b = blockIdx.x;
  int f0 = 2 * b, f1 = 2 * b + 1;
  int v = 0, vS = 0;
  if (t < P1) {
    v = hist2d[f0 * P1 + t];
    vS = shist2d[f0 * P1 + t];
    if (f1 < NBH) { v += hist2d[f1 * P1 + t]; vS += shist2d[f1 * P1 + t]; }
    lbase[t] = pbase[t] + colpre[f0 * P1 + t];
    lbaseS[t] = pbaseS[t] + colpreS[f0 * P1 + t];
    lcur[t] = 0;
    lcurS[t] = 0;
  }
  int x = v;
  sm[t] = x;
  __syncthreads();
  for (int off = 1; off < 256; off <<= 1) {
    int y = (t >= off) ? sm[t - off] : 0;
    __syncthreads();
    x += y;
    sm[t] = x;
    __syncthreads();
  }
  if (t < P1) lofs[t] = x - v;
  __syncthreads();
  int xS = vS;
  sm[t] = xS;
  __syncthreads();
  for (int off = 1; off < 256; off <<= 1) {
    int y = (t >= off) ? sm[t - off] : 0;
    __syncthreads();
    xS += y;
    sm[t] = xS;
    __syncthreads();
  }
  if (t < P1) lofsS[t] = xS - vS;
  __syncthreads();

  int base = b * EPB_P;
  int cnt = NE - base; if (cnt > EPB_P) cnt = EPB_P;
  for (int i = t; i < cnt; i += 256) {
    int s = src[base + i], d = dst[base + i];
    int p = d >> SH1;
    int pos = lofs[p] + atomicAdd(&lcur[p], 1);
    buf[pos] = ((unsigned)s << SH1) | (unsigned)(d & 511);
    prt[pos] = (unsigned char)p;
    int pS = s >> SH1;
    int posS = lofsS[pS] + atomicAdd(&lcurS[pS], 1);
    bufS[posS] = (unsigned)s;
  }
  __syncthreads();
  for (int i = t; i < cnt; i += 256) {
    int p = prt[i];
    staged[lbase[p] + (i - lofs[p])] = buf[i];
    unsigned sv = bufS[i];
    int pS = sv >> SH1;
    stagedS[lbaseS[pS] + (i - lofsS[pS])] = (unsigned short)(sv & 511);
  }
}

// ---------------- pass D: per-partition CSR build (+ inorm) ----------------
__global__ __launch_bounds__(512) void k_buildp(const unsigned* __restrict__ staged, const int* __restrict__ totals,
                                                const int* __restrict__ pbase, int* __restrict__ rp,
                                                float* __restrict__ inorm, int* __restrict__ csr) {
  __shared__ int lcnt[512], lofs[512], lcur[512];
  int p = blockIdx.x, t = threadIdx.x;
  int pb = pbase[p], cnt = totals[p];
  lcnt[t] = 0;
  __syncthreads();
  const unsigned* sp = staged + pb;
  for (int i = t; i < cnt; i += 512) atomicAdd(&lcnt[sp[i] & 511], 1);
  __syncthreads();
  int v = lcnt[t];
  int x = v;
  lofs[t] = x;
  __syncthreads();
  for (int off = 1; off < 512; off <<= 1) {
    int y = (t >= off) ? lofs[t - off] : 0;
    __syncthreads();
    x += y;
    lofs[t] = x;
    __syncthreads();
  }
  int excl = x - v;
  lofs[t] = excl;
  lcur[t] = 0;
  int node = (p << SH1) + t;
  if (node < NN) {
    rp[node] = pb + excl;
    int dg = v < 1 ? 1 : v;
    inorm[node] = rsqrtf((float)dg);
  }
  __syncthreads();
  for (int i = t; i < cnt; i += 512) {
    unsigned e = sp[i];
    int d = e & 511;
    int pos = pb + lofs[d] + atomicAdd(&lcur[d], 1);
    csr[pos] = (int)(e >> SH1);
  }
}

// ---------------- pass E: per-partition src count -> onorm ----------------
__global__ __launch_bounds__(512) void k_countS(const unsigned short* __restrict__ stagedS,
                                                const int* __restrict__ totalsS, const int* __restrict__ pbaseS,
                                                float* __restrict__ onorm) {
  __shared__ int lcnt[512];
  int p = blockIdx.x, t = threadIdx.x;
  int pb = pbaseS[p], cnt = totalsS[p];
  lcnt[t] = 0;
  __syncthreads();
  const unsigned short* sp = stagedS + pb;
  for (int i = t; i < cnt; i += 512) atomicAdd(&lcnt[sp[i]], 1);
  __syncthreads();
  int node = (p << SH1) + t;
  if (node < NN) {
    int od = lcnt[t];
    if (od < 1) od = 1;
    onorm[node] = rsqrtf((float)od);
  }
}

// ---------------- weight pack: fragment-major f16 for mfma 16x16x32 ----------------
template <int K, int NW>
__global__ __launch_bounds__(256) void k_packw(const float* __restrict__ W, f16* __restrict__ Wp) {
  int idx = blockIdx.x * 256 + threadIdx.x;
  if (idx >= K * NW) return;
  constexpr int nT = NW / 16;
  int i = idx & 7;
  int l = (idx >> 3) & 63;
  int rest = idx >> 9;
  int t = rest % nT;
  int s = rest / nT;
  int k = s * 32 + (l >> 4) * 8 + i;
  int n = t * 16 + (l & 15);
  Wp[idx] = (f16)W[k * NW + n];
}

// ---------------- GEMM: [M=NN x K] @ [K x NW] via mfma_f32_16x16x32_f16 ----------------
// MODE 0 (layer 1): x f32 staged through LDS with LINEAR coalesced loads — thread t
//   loads tile elements [it*2048 + t*8, +8): each instruction's 64 lanes read 2KB
//   CONTIGUOUS (R19 bug: per-row decomposition kept the 64-line scatter).
//   XPITCH=280 (560B = 140 words = 12 mod 32 -> 2-way LDS aliasing, free per m136;
//   R19's 264 gave 8-way = 1.4M conflicts).
// MODE 1: A = f16 sliced-32, plain store.                (layer 3)
// MODE 2: A = f16 sliced-32; epilogue relu(+bias)*onorm. (layer 2)
#define XPITCH 280
template <int K, int NW, int MODE>
__global__ __launch_bounds__(256) void k_gemm(const void* __restrict__ Asrc, const f16* __restrict__ Wp,
                                              const float* __restrict__ onorm, const float* __restrict__ bias,
                                              f16* __restrict__ Out) {
  constexpr int nS = K / 32, nT = NW / 16;
  int lane = threadIdx.x & 63;
  int w = threadIdx.x >> 6;
  int bm = blockIdx.x * 64 + w * 16;
  int arow = bm + (lane & 15);
  int koff = (lane >> 4) * 8;
  bool rowok = arow < NN;

  __shared__ f16 axs[MODE == 0 ? 64 * XPITCH : 1];

  if (MODE == 0) {
    // stage 64x256 f32 tile -> scaled f16 LDS tile, LINEAR layout (coalesced)
    int t = threadIdx.x;
    int grow0 = blockIdx.x * 64;
#pragma unroll
    for (int it = 0; it < 8; ++it) {
      int off = it * 2048 + t * 8;     // element offset within the 64x256 tile
      int lrow = off >> 8;             // 0..63
      int lcol = off & 255;
      int grow = grow0 + lrow;
      bool gok = grow < NN;
      float on = gok ? onorm[grow] : 0.0f;
      f32x4 v0 = {}, v1 = {};
      if (gok) {
        const float* xp = (const float*)Asrc + (size_t)grow * K + lcol;
        v0 = *(const f32x4*)xp;
        v1 = *(const f32x4*)(xp + 4);
      }
      f16x8 o;
#pragma unroll
      for (int j = 0; j < 4; ++j) {
        o[j] = (f16)(v0[j] * on);
        o[4 + j] = (f16)(v1[j] * on);
      }
      *(f16x8*)(axs + lrow * XPITCH + lcol) = o;
    }
    __syncthreads();
  }

  f32x4 acc[nT];
#pragma unroll
  for (int t = 0; t < nT; ++t) acc[t] = (f32x4){0.f, 0.f, 0.f, 0.f};

  for (int s = 0; s < nS; ++s) {
    f16x8 a = {};
    if (MODE == 0) {
      a = *(const f16x8*)(axs + (w * 16 + (lane & 15)) * XPITCH + s * 32 + koff);
    } else if (rowok) {
      // sliced-32 A: k-subtile s IS slice s
      a = *(const f16x8*)((const f16*)Asrc + ((size_t)s * NN + arow) * 32 + koff);
    }
    const f16* bp = Wp + ((size_t)(s * nT) * 64 + lane) * 8;
#pragma unroll
    for (int t = 0; t < nT; ++t) {
      f16x8 bfr = *(const f16x8*)(bp + t * 512);
      acc[t] = __builtin_amdgcn_mfma_f32_16x16x32_f16(a, bfr, acc[t], 0, 0, 0);
    }
  }

  int crow0 = bm + (lane >> 4) * 4;
  int ccol = lane & 15;
#pragma unroll
  for (int t = 0; t < nT; ++t) {
#pragma unroll
    for (int r = 0; r < 4; ++r) {
      int row = crow0 + r;
      if (row >= NN) continue;
      int col = t * 16 + ccol;
      float v = acc[t][r];
      if (MODE == 2) v = fmaxf(v + bias[col], 0.f) * onorm[row];
      Out[((size_t)(col >> 5) * NN + row) * 32 + (col & 31)] = (f16)v;
    }
  }
}

// ---------------- sliced aggregation: 64B rows, 4 lanes/node, LDS-staged indices ----------
#define LCSR_CAP 1408  // 64 nodes * mean 16 = 1024, sigma 32 -> +12 sigma
template <int NS, int MODE>
__global__ __launch_bounds__(256) void k_aggs(const f16* __restrict__ src_arr, const int* __restrict__ rp,
                                              const int* __restrict__ csr, const float* __restrict__ inorm,
                                              const float* __restrict__ onorm, const float* __restrict__ bias,
                                              void* __restrict__ outp) {
  constexpr int XPS = 8 / NS;              // XCDs per slice
  constexpr int BPS = (NN + 63) / 64;      // node-groups per slice = 1563
  __shared__ int lcsr[LCSR_CAP];
  int bid = blockIdx.x;
  int r = bid & 7;
  int slice = r / XPS;
  int w = (bid >> 3) * XPS + (r % XPS);
  if (w >= BPS) return;                    // uniform per block
  int t = threadIdx.x;
  int nbase = w * 64;
  int nlim = nbase + 64; if (nlim > NN) nlim = NN;
  int first = rp[nbase];
  int last = rp[nlim];
  int span = last - first;
  bool useLds = (span <= LCSR_CAP);
  if (useLds) {
    for (int i = t; i < span; i += 256) lcsr[i] = csr[first + i];
  }
  __syncthreads();
  int node = nbase + (t >> 2);
  if (node >= NN) return;
  int q = t & 3;                           // quarter of the 64B row
  int beg = rp[node], end = rp[node + 1];
  const char* sbp = (const char*)src_arr + ((size_t)slice * NN * 32 + q * 8) * 2;

  float acc[8];
#pragma unroll
  for (int j = 0; j < 8; ++j) acc[j] = 0.f;

  if (useLds) {
    int le = beg - first, lend = end - first;
    for (; le + 7 < lend; le += 8) {
      int x0 = lcsr[le], x1 = lcsr[le + 1], x2 = lcsr[le + 2], x3 = lcsr[le + 3];
      int x4 = lcsr[le + 4], x5 = lcsr[le + 5], x6 = lcsr[le + 6], x7 = lcsr[le + 7];
      f16x8 v0 = *(const f16x8*)(sbp + ((size_t)(unsigned)x0 << 6));
      f16x8 v1 = *(const f16x8*)(sbp + ((size_t)(unsigned)x1 << 6));
      f16x8 v2 = *(const f16x8*)(sbp + ((size_t)(unsigned)x2 << 6));
      f16x8 v3 = *(const f16x8*)(sbp + ((size_t)(unsigned)x3 << 6));
      f16x8 v4 = *(const f16x8*)(sbp + ((size_t)(unsigned)x4 << 6));
      f16x8 v5 = *(const f16x8*)(sbp + ((size_t)(unsigned)x5 << 6));
      f16x8 v6 = *(const f16x8*)(sbp + ((size_t)(unsigned)x6 << 6));
      f16x8 v7 = *(const f16x8*)(sbp + ((size_t)(unsigned)x7 << 6));
#pragma unroll
      for (int j = 0; j < 8; ++j) {
        float s01 = (float)v0[j] + (float)v1[j];
        float s23 = (float)v2[j] + (float)v3[j];
        float s45 = (float)v4[j] + (float)v5[j];
        float s67 = (float)v6[j] + (float)v7[j];
        acc[j] += (s01 + s23) + (s45 + s67);
      }
    }
    for (; le + 3 < lend; le += 4) {
      int x0 = lcsr[le], x1 = lcsr[le + 1], x2 = lcsr[le + 2], x3 = lcsr[le + 3];
      f16x8 v0 = *(const f16x8*)(sbp + ((size_t)(unsigned)x0 << 6));
      f16x8 v1 = *(const f16x8*)(sbp + ((size_t)(unsigned)x1 << 6));
      f16x8 v2 = *(const f16x8*)(sbp + ((size_t)(unsigned)x2 << 6));
      f16x8 v3 = *(const f16x8*)(sbp + ((size_t)(unsigned)x3 << 6));
#pragma unroll
      for (int j = 0; j < 8; ++j)
        acc[j] += ((float)v0[j] + (float)v1[j]) + ((float)v2[j] + (float)v3[j]);
    }
    for (; le < lend; ++le) {
      f16x8 v0 = *(const f16x8*)(sbp + ((size_t)(unsigned)lcsr[le] << 6));
#pragma unroll
      for (int j = 0; j < 8; ++j) acc[j] += (float)v0[j];
    }
  } else {
    for (int e = beg; e < end; ++e) {
      f16x8 v0 = *(const f16x8*)(sbp + ((size_t)(unsigned)csr[e] << 6));
#pragma unroll
      for (int j = 0; j < 8; ++j) acc[j] += (float)v0[j];
    }
  }

  float inn = inorm[node];
  int gfb = slice * 32 + q * 8;            // global feature col base
  if (MODE == 0) {
    float on = onorm[node];
    f16x8 o;
#pragma unroll
    for (int j = 0; j < 8; ++j) o[j] = (f16)(fmaxf(acc[j] * inn + bias[gfb + j], 0.f) * on);
    *(f16x8*)((f16*)outp + ((size_t)slice * NN + node) * 32 + q * 8) = o;
  } else if (MODE == 1) {
    f16x8 o;
#pragma unroll
    for (int j = 0; j < 8; ++j) o[j] = (f16)(acc[j] * inn);
    *(f16x8*)((f16*)outp + ((size_t)slice * NN + node) * 32 + q * 8) = o;
  } else {
    float* op = (float*)outp + (size_t)node * (NS * 32) + gfb;
    f32x4 o0, o1;
#pragma unroll
    for (int j = 0; j < 4; ++j) {
      o0[j] = acc[j] * inn + bias[gfb + j];
      o1[j] = acc[4 + j] * inn + bias[gfb + 4 + j];
    }
    *(f32x4*)op = o0;
    *(f32x4*)(op + 4) = o1;
  }
}

extern "C" void kernel_launch(void* const* d_in, const int* in_sizes, int n_in,
                              void* d_out, int out_size, void* d_ws, size_t ws_size,
                              hipStream_t stream) {
  const float* x = (const float*)d_in[0];
  const int* src = (const int*)d_in[1];
  const int* dst = (const int*)d_in[2];
  const float* W1 = (const float*)d_in[3];
  const float* b1 = (const float*)d_in[4];
  const float* W2 = (const float*)d_in[5];
  const float* b2 = (const float*)d_in[6];
  const float* W3 = (const float*)d_in[7];
  const float* b3 = (const float*)d_in[8];

  char* base = (char*)d_ws;
  size_t off = 0;
  auto take = [&](size_t bytes) -> void* {
    void* r = base + off;
    off += (bytes + 255) & ~(size_t)255;
    return r;
  };
  float* onorm = (float*)take((size_t)NN * 4);
  float* inorm = (float*)take((size_t)NN * 4);
  int* rp = (int*)take((size_t)(NN + 1) * 4);
  int* totals = (int*)take((size_t)P1 * 4);
  int* totalsS = (int*)take((size_t)P1 * 4);
  int* pbase = (int*)take((size_t)P1 * 4);
  int* pbaseS = (int*)take((size_t)P1 * 4);
  int* hist2d = (int*)take((size_t)NBH * P1 * 4);
  int* shist2d = (int*)take((size_t)NBH * P1 * 4);
  int* colpre = (int*)take((size_t)NBH * P1 * 4);
  int* colpreS = (int*)take((size_t)NBH * P1 * 4);
  unsigned* staged = (unsigned*)take((size_t)NE * 4);
  unsigned short* stagedS = (unsigned short*)take((size_t)NE * 2);
  int* csr = (int*)take((size_t)NE * 4);
  f16* W1p = (f16*)take((size_t)FIN * FHID * 2);
  f16* W2p = (f16*)take((size_t)FHID * FHID * 2);
  f16* W3p = (f16*)take((size_t)FHID * FCLS * 2);
  f16* B1 = (f16*)take((size_t)NN * FHID * 2);
  f16* B2 = (f16*)take((size_t)NN * FHID * 2);

  k_histA<<<NBH, 256, 0, stream>>>(src, dst, hist2d, shist2d);
  k_colscan2<<<2 * P1, 256, 0, stream>>>(hist2d, shist2d, colpre, colpreS, totals, totalsS);
  k_pbase2<<<1, 256, 0, stream>>>(totals, totalsS, pbase, pbaseS, rp);
  k_place<<<NBP, 256, 0, stream>>>(src, dst, hist2d, shist2d, colpre, colpreS, pbase, pbaseS, staged, stagedS);
  k_buildp<<<P1, 512, 0, stream>>>(staged, totals, pbase, rp, inorm, csr);
  k_countS<<<P1, 512, 0, stream>>>(stagedS, totalsS, pbaseS, onorm);

  k_packw<FIN, FHID><<<(FIN * FHID + 255) / 256, 256, 0, stream>>>(W1, W1p);
  k_packw<FHID, FHID><<<(FHID * FHID + 255) / 256, 256, 0, stream>>>(W2, W2p);
  k_packw<FHID, FCLS><<<(FHID * FCLS + 255) / 256, 256, 0, stream>>>(W3, W3p);

  const int gemm_grid = (NN + 63) / 64;
  const int bps = (NN + 63) / 64;              // 1563
  const int agg4_grid = ((bps + 1) / 2) * 8;   // 6256 (NS=4, XPS=2)
  const int agg2_grid = ((bps + 3) / 4) * 8;   // 3128 (NS=2, XPS=4)

  // layer 1: t1 = (x*onorm) @ W1  -> sliced-32 B1 (4 slices), LDS-staged A
  k_gemm<FIN, FHID, 0><<<gemm_grid, 256, 0, stream>>>(x, W1p, onorm, nullptr, B1);
  // g1 = relu(agg(t1)*inorm + b1) * onorm  -> sliced-32 B2
  k_aggs<4, 0><<<agg4_grid, 256, 0, stream>>>(B1, rp, csr, inorm, onorm, b1, B2);
  // agg2 = agg(g1)*inorm  -> sliced-32 B1
  k_aggs<4, 1><<<agg4_grid, 256, 0, stream>>>(B2, rp, csr, inorm, nullptr, nullptr, B1);
  // g2 = relu(agg2 @ W2 + b2) * onorm  -> sliced-32 B2
  k_gemm<FHID, FHID, 2><<<gemm_grid, 256, 0, stream>>>(B1, W2p, onorm, b2, B2);
  // t3 = g2 @ W3  -> sliced-32 B1 (2 slices used)
  k_gemm<FHID, FCLS, 1><<<gemm_grid, 256, 0, stream>>>(B2, W3p, nullptr, nullptr, B1);
  // out = agg(t3)*inorm + b3  -> dense f32 d_out
  k_aggs<2, 2><<<agg2_grid, 256, 0, stream>>>(B1, rp, csr, inorm, nullptr, b3, d_out);
}